// Round 1
// baseline (11775.672 us; speedup 1.0000x reference)
//
#include <hip/hip_runtime.h>
#include <cmath>

// GPT-2 small forward (B=2,T=1024,L=12,C=768,FF=3072,H=12,D=64,V=50257)
// fp32 residual stream + bf16 MFMA GEMMs + fp32 flash attention.

using u16 = unsigned short;
using u32 = unsigned int;
using f32x4 = __attribute__((ext_vector_type(4))) float;
using u32x4 = __attribute__((ext_vector_type(4))) unsigned int;

#define GLD_LDS16(g, l)                                      \
  __builtin_amdgcn_global_load_lds(                          \
      (const __attribute__((address_space(1))) void*)(g),    \
      (__attribute__((address_space(3))) void*)(l), 16, 0, 0)

__device__ __forceinline__ u16 f2bf(float f) {
  u32 u = __float_as_uint(f);
  return (u16)((u + 0x7fffu + ((u >> 16) & 1u)) >> 16);
}
__device__ __forceinline__ float bflo(u32 u) { return __uint_as_float(u << 16); }
__device__ __forceinline__ float bfhi(u32 u) { return __uint_as_float(u & 0xffff0000u); }

// ---------------------------------------------------------------- cvt fp32->bf16 (pads dst with zeros past n_src)
__global__ __launch_bounds__(256) void cvt_f32_bf16(const float* __restrict__ src,
                                                    u16* __restrict__ dst,
                                                    int n_src, int n_dst) {
  int i4 = blockIdx.x * 256 + threadIdx.x;  // float4 index
  if (i4 * 4 >= n_dst) return;
  float4 v = make_float4(0.f, 0.f, 0.f, 0.f);
  if (i4 * 4 < n_src) v = ((const float4*)src)[i4];
  uint2 o;
  o.x = (u32)f2bf(v.x) | ((u32)f2bf(v.y) << 16);
  o.y = (u32)f2bf(v.z) | ((u32)f2bf(v.w) << 16);
  ((uint2*)dst)[i4] = o;
}

// ---------------------------------------------------------------- embedding: x = tok_embed[tok] + pos_embed[t]
__global__ __launch_bounds__(256) void embed_kernel(const int* __restrict__ tokens,
                                                    const float* __restrict__ te,
                                                    const float* __restrict__ pe,
                                                    float* __restrict__ x) {
  int idx = blockIdx.x * 256 + threadIdx.x;  // 0 .. 2048*192-1
  int row = idx / 192, c = (idx % 192) * 4;
  int tok = tokens[row];
  float4 a = *(const float4*)(te + (size_t)tok * 768 + c);
  float4 p = *(const float4*)(pe + (size_t)(row & 1023) * 768 + c);
  a.x += p.x; a.y += p.y; a.z += p.z; a.w += p.w;
  *(float4*)(x + (size_t)row * 768 + c) = a;
}

// ---------------------------------------------------------------- LayerNorm (fp32 in) -> bf16 out; one wave per row
__global__ __launch_bounds__(256) void ln_kernel(const float* __restrict__ x,
                                                 const float* __restrict__ w,
                                                 const float* __restrict__ b,
                                                 u16* __restrict__ y, int nrows) {
  int row = blockIdx.x * 4 + (threadIdx.x >> 6);
  int lane = threadIdx.x & 63;
  if (row >= nrows) return;
  const float* xr = x + (size_t)row * 768;
  float v[12];
  float s = 0.f;
#pragma unroll
  for (int i = 0; i < 12; i++) { v[i] = xr[lane + i * 64]; s += v[i]; }
#pragma unroll
  for (int off = 32; off; off >>= 1) s += __shfl_xor(s, off, 64);
  float mean = s * (1.f / 768.f);
  float var = 0.f;
#pragma unroll
  for (int i = 0; i < 12; i++) { float d = v[i] - mean; var += d * d; }
#pragma unroll
  for (int off = 32; off; off >>= 1) var += __shfl_xor(var, off, 64);
  float rs = rsqrtf(var * (1.f / 768.f) + 1e-5f);
  u16* yr = y + (size_t)row * 768;
#pragma unroll
  for (int i = 0; i < 12; i++) {
    int c = lane + i * 64;
    yr[c] = f2bf((v[i] - mean) * rs * w[c] + b[c]);
  }
}

// ---------------------------------------------------------------- GEMM: out[M,N] = A[M,K](bf16) @ Bw[N,K]^T(bf16) (+epilogue)
// 128x128 tile, BK=32, 4 waves (2x2), mfma 16x16x32 bf16, double-buffered LDS,
// global_load_lds dwordx4 staging (linear LDS layout; swizzle is a later round).
#define EPI_QKV 0
#define EPI_RESID 1
#define EPI_GELU 2
#define EPI_LM 3

template <int EPI>
__global__ __launch_bounds__(256) void gemm_bt(const u16* __restrict__ A,
                                               const u16* __restrict__ Bw,
                                               const float* __restrict__ bias,
                                               const float* __restrict__ resid,
                                               void* __restrict__ outv,
                                               int K, int ldout, int nstore) {
  __shared__ u16 As[2][128 * 32];
  __shared__ u16 Bs[2][128 * 32];
  const int tid = threadIdx.x;
  const int w = tid >> 6, lane = tid & 63;
  const int m0 = blockIdx.y << 7, n0 = blockIdx.x << 7;
  const int wm = w >> 1, wn = w & 1;
  const int lr = lane & 15, lg = lane >> 4;
  const int c0 = tid, c1 = tid + 256;  // 16B-chunk ids; chunk c -> row c>>2, k-part (c&3)*8
  const u16* ga0 = A + (size_t)(m0 + (c0 >> 2)) * K + (c0 & 3) * 8;
  const u16* ga1 = A + (size_t)(m0 + (c1 >> 2)) * K + (c1 & 3) * 8;
  const u16* gb0 = Bw + (size_t)(n0 + (c0 >> 2)) * K + (c0 & 3) * 8;
  const u16* gb1 = Bw + (size_t)(n0 + (c1 >> 2)) * K + (c1 & 3) * 8;

  f32x4 acc[4][4] = {};
  const int nk = K >> 5;

  auto stage = [&](int buf, int kt) {
    const int k0 = kt << 5;
    GLD_LDS16(ga0 + k0, &As[buf][(w * 64) * 8]);
    GLD_LDS16(ga1 + k0, &As[buf][(256 + w * 64) * 8]);
    GLD_LDS16(gb0 + k0, &Bs[buf][(w * 64) * 8]);
    GLD_LDS16(gb1 + k0, &Bs[buf][(256 + w * 64) * 8]);
  };

  auto compute = [&](int buf) {
    u32x4 a[4], b[4];
#pragma unroll
    for (int i = 0; i < 4; i++) {
      a[i] = *(const u32x4*)&As[buf][(wm * 64 + i * 16 + lr) * 32 + lg * 8];
      b[i] = *(const u32x4*)&Bs[buf][(wn * 64 + i * 16 + lr) * 32 + lg * 8];
    }
#pragma unroll
    for (int mi = 0; mi < 4; mi++)
#pragma unroll
      for (int ni = 0; ni < 4; ni++)
        asm("v_mfma_f32_16x16x32_bf16 %0, %1, %2, %0"
            : "+v"(acc[mi][ni])
            : "v"(a[mi]), "v"(b[ni]));
  };

  stage(0, 0);
  __syncthreads();
  int cur = 0;
  for (int kt = 0; kt < nk - 1; kt++) {
    stage(cur ^ 1, kt + 1);
    compute(cur);
    __syncthreads();
    cur ^= 1;
  }
  compute(cur);
  __builtin_amdgcn_sched_barrier(0);
  asm volatile("s_nop 7\ns_nop 7");  // MFMA->VALU hazard spacing (inline-asm mfma)
  __builtin_amdgcn_sched_barrier(0);

  // D mapping (m89-verified): col = lane&15, row = (lane>>4)*4 + reg
  const int row0 = m0 + wm * 64 + lg * 4;
  const int col0 = n0 + wn * 64 + lr;
#pragma unroll
  for (int ni = 0; ni < 4; ni++) {
    const int col = col0 + ni * 16;
    float bv = 0.f;
    if constexpr (EPI != EPI_LM) bv = bias[col];
#pragma unroll
    for (int mi = 0; mi < 4; mi++) {
#pragma unroll
      for (int r2 = 0; r2 < 4; r2++) {
        const int row = row0 + mi * 16 + r2;
        const float v = acc[mi][ni][r2] + bv;
        if constexpr (EPI == EPI_QKV) {
          ((u16*)outv)[(size_t)row * ldout + col] = f2bf(v);
        } else if constexpr (EPI == EPI_RESID) {
          ((float*)outv)[(size_t)row * ldout + col] =
              resid[(size_t)row * ldout + col] + v;
        } else if constexpr (EPI == EPI_GELU) {
          const float t = 0.7978845608f * (v + 0.044715f * v * v * v);
          const float g = 0.5f * v * (1.f + tanhf(t));
          ((u16*)outv)[(size_t)row * ldout + col] = f2bf(g);
        } else {  // EPI_LM
          if (col < nstore)
            ((float*)outv)[(size_t)row * (size_t)ldout + col] = v;
        }
      }
    }
  }
}

// ---------------------------------------------------------------- causal flash attention, fp32, lane-per-q-row
// grid: 24 (b*h) * 4 (q blocks of 256) blocks; 4 waves/block; wave = 64 q rows.
__global__ __launch_bounds__(256) void attn_kernel(const u16* __restrict__ qkv,
                                                   u16* __restrict__ ao) {
  __shared__ float kt[64][64];
  __shared__ float vt[64][64];
  const int bid = blockIdx.x;
  const int bh = bid >> 2, qblk = bid & 3;
  const int b = bh / 12, h = bh % 12;
  const int tid = threadIdx.x, w = tid >> 6, lane = tid & 63;
  const int q = qblk * 256 + w * 64 + lane;
  const size_t base = (size_t)(b * 1024) * 2304;

  float qr[64];
  {
    const uint4* qp = (const uint4*)(qkv + base + (size_t)q * 2304 + h * 64);
#pragma unroll
    for (int i = 0; i < 8; i++) {
      uint4 u = qp[i];
      qr[i * 8 + 0] = bflo(u.x) * 0.125f; qr[i * 8 + 1] = bfhi(u.x) * 0.125f;
      qr[i * 8 + 2] = bflo(u.y) * 0.125f; qr[i * 8 + 3] = bfhi(u.y) * 0.125f;
      qr[i * 8 + 4] = bflo(u.z) * 0.125f; qr[i * 8 + 5] = bfhi(u.z) * 0.125f;
      qr[i * 8 + 6] = bflo(u.w) * 0.125f; qr[i * 8 + 7] = bfhi(u.w) * 0.125f;
    }
  }
  float o[64];
#pragma unroll
  for (int d = 0; d < 64; d++) o[d] = 0.f;
  float m = -1e30f, l = 0.f;

  const int ntiles = qblk * 4 + 4;
  const int r = tid >> 2, cc = (tid & 3) * 16;  // staging: row r, d-range [cc, cc+16)
  const u16* krow = qkv + base + (size_t)r * 2304 + 768 + h * 64 + cc;
  const u16* vrow = qkv + base + (size_t)r * 2304 + 1536 + h * 64 + cc;
  const int q0w = qblk * 256 + w * 64;

  for (int t = 0; t < ntiles; t++) {
    __syncthreads();  // previous tile fully consumed
    {
      const uint4* kp = (const uint4*)(krow + (size_t)t * 64 * 2304);
      const uint4* vp = (const uint4*)(vrow + (size_t)t * 64 * 2304);
      float4* kd = (float4*)&kt[r][cc];
      float4* vd = (float4*)&vt[r][cc];
#pragma unroll
      for (int i = 0; i < 2; i++) {
        uint4 u = kp[i];
        kd[i * 2 + 0] = make_float4(bflo(u.x), bfhi(u.x), bflo(u.y), bfhi(u.y));
        kd[i * 2 + 1] = make_float4(bflo(u.z), bfhi(u.z), bflo(u.w), bfhi(u.w));
        uint4 v2 = vp[i];
        vd[i * 2 + 0] = make_float4(bflo(v2.x), bfhi(v2.x), bflo(v2.y), bfhi(v2.y));
        vd[i * 2 + 1] = make_float4(bflo(v2.z), bfhi(v2.z), bflo(v2.w), bfhi(v2.w));
      }
    }
    __syncthreads();
    int jmax = q0w + 63 - t * 64;
    if (jmax > 63) jmax = 63;
    for (int j = 0; j <= jmax; j++) {
      const float4* k4 = (const float4*)&kt[j][0];
      float s = 0.f;
#pragma unroll
      for (int dq = 0; dq < 16; dq++) {
        float4 kk = k4[dq];
        s += qr[dq * 4 + 0] * kk.x + qr[dq * 4 + 1] * kk.y +
             qr[dq * 4 + 2] * kk.z + qr[dq * 4 + 3] * kk.w;
      }
      const bool valid = (t * 64 + j) <= q;
      s = valid ? s : -1e30f;
      if (s > m) {  // rescale (rare after warmup)
        float corr = __expf(m - s);
        l *= corr;
#pragma unroll
        for (int d = 0; d < 64; d++) o[d] *= corr;
        m = s;
      }
      float p = valid ? __expf(s - m) : 0.f;
      l += p;
      const float4* v4 = (const float4*)&vt[j][0];
#pragma unroll
      for (int dq = 0; dq < 16; dq++) {
        float4 vv = v4[dq];
        o[dq * 4 + 0] += p * vv.x; o[dq * 4 + 1] += p * vv.y;
        o[dq * 4 + 2] += p * vv.z; o[dq * 4 + 3] += p * vv.w;
      }
    }
  }

  const float inv = 1.f / l;
  u16* orow = ao + (size_t)(b * 1024 + q) * 768 + h * 64;
#pragma unroll
  for (int i = 0; i < 8; i++) {
    uint4 u;
    u.x = (u32)f2bf(o[i * 8 + 0] * inv) | ((u32)f2bf(o[i * 8 + 1] * inv) << 16);
    u.y = (u32)f2bf(o[i * 8 + 2] * inv) | ((u32)f2bf(o[i * 8 + 3] * inv) << 16);
    u.z = (u32)f2bf(o[i * 8 + 4] * inv) | ((u32)f2bf(o[i * 8 + 5] * inv) << 16);
    u.w = (u32)f2bf(o[i * 8 + 6] * inv) | ((u32)f2bf(o[i * 8 + 7] * inv) << 16);
    *(uint4*)(orow + i * 8) = u;
  }
}

// ----------------------------------------------------------------
extern "C" void kernel_launch(void* const* d_in, const int* in_sizes, int n_in,
                              void* d_out, int out_size, void* d_ws, size_t ws_size,
                              hipStream_t stream) {
  (void)in_sizes; (void)n_in; (void)out_size; (void)ws_size;
  const int*   tokens    = (const int*)d_in[0];
  const float* tok_embed = (const float*)d_in[1];
  const float* pos_embed = (const float*)d_in[2];
  const float* ln1_w = (const float*)d_in[3];
  const float* ln1_b = (const float*)d_in[4];
  const float* qkv_w = (const float*)d_in[5];
  const float* qkv_b = (const float*)d_in[6];
  const float* proj_w = (const float*)d_in[7];
  const float* proj_b = (const float*)d_in[8];
  const float* ln2_w = (const float*)d_in[9];
  const float* ln2_b = (const float*)d_in[10];
  const float* fc_w = (const float*)d_in[11];
  const float* fc_b = (const float*)d_in[12];
  const float* fc2_w = (const float*)d_in[13];
  const float* fc2_b = (const float*)d_in[14];
  const float* lnf_w = (const float*)d_in[15];
  const float* lnf_b = (const float*)d_in[16];
  float* out = (float*)d_out;

  char* ws = (char*)d_ws;
  size_t off = 0;
  auto galloc = [&](size_t bytes) -> void* {
    void* p = ws + off;
    off += (bytes + 255) & ~(size_t)255;
    return p;
  };
  float* x  = (float*)galloc(2048ull * 768 * 4);   // fp32 residual stream
  u16* y    = (u16*)galloc(2048ull * 768 * 2);     // bf16 LN output
  u16* qkv  = (u16*)galloc(2048ull * 2304 * 2);
  u16* ao   = (u16*)galloc(2048ull * 768 * 2);
  u16* hh   = (u16*)galloc(2048ull * 3072 * 2);
  u16* wq   = (u16*)galloc(2304ull * 768 * 2);
  u16* wp   = (u16*)galloc(768ull * 768 * 2);
  u16* wf   = (u16*)galloc(3072ull * 768 * 2);
  u16* wf2  = (u16*)galloc(768ull * 3072 * 2);
  u16* emb  = (u16*)galloc(50304ull * 768 * 2);    // V padded to 393*128

  // tied-embedding bf16 copy (zero-padded rows 50257..50303)
  {
    const int nsrc = 50257 * 768, ndst = 50304 * 768;
    cvt_f32_bf16<<<(ndst / 4 + 255) / 256, 256, 0, stream>>>(tok_embed, emb, nsrc, ndst);
  }
  embed_kernel<<<1536, 256, 0, stream>>>(tokens, tok_embed, pos_embed, x);

  for (int l = 0; l < 12; l++) {
    cvt_f32_bf16<<<(2304 * 768 / 4 + 255) / 256, 256, 0, stream>>>(
        qkv_w + (size_t)l * 2304 * 768, wq, 2304 * 768, 2304 * 768);
    cvt_f32_bf16<<<(768 * 768 / 4 + 255) / 256, 256, 0, stream>>>(
        proj_w + (size_t)l * 768 * 768, wp, 768 * 768, 768 * 768);
    cvt_f32_bf16<<<(3072 * 768 / 4 + 255) / 256, 256, 0, stream>>>(
        fc_w + (size_t)l * 3072 * 768, wf, 3072 * 768, 3072 * 768);
    cvt_f32_bf16<<<(3072 * 768 / 4 + 255) / 256, 256, 0, stream>>>(
        fc2_w + (size_t)l * 768 * 3072, wf2, 768 * 3072, 768 * 3072);

    ln_kernel<<<512, 256, 0, stream>>>(x, ln1_w + l * 768, ln1_b + l * 768, y, 2048);
    gemm_bt<EPI_QKV><<<dim3(18, 16), 256, 0, stream>>>(
        y, wq, qkv_b + l * 2304, nullptr, qkv, 768, 2304, 2304);
    attn_kernel<<<96, 256, 0, stream>>>(qkv, ao);
    gemm_bt<EPI_RESID><<<dim3(6, 16), 256, 0, stream>>>(
        ao, wp, proj_b + l * 768, x, x, 768, 768, 768);
    ln_kernel<<<512, 256, 0, stream>>>(x, ln2_w + l * 768, ln2_b + l * 768, y, 2048);
    gemm_bt<EPI_GELU><<<dim3(24, 16), 256, 0, stream>>>(
        y, wf, fc_b + l * 3072, nullptr, hh, 768, 3072, 3072);
    gemm_bt<EPI_RESID><<<dim3(6, 16), 256, 0, stream>>>(
        hh, wf2, fc2_b + l * 768, x, x, 3072, 768, 768);
  }

  ln_kernel<<<512, 256, 0, stream>>>(x, lnf_w, lnf_b, y, 2048);
  gemm_bt<EPI_LM><<<dim3(393, 16), 256, 0, stream>>>(
      y, emb, nullptr, nullptr, out, 768, 50257, 50257);
}